// Round 5
// baseline (1006.066 us; speedup 1.0000x reference)
//
#include <hip/hip_runtime.h>
#include <math.h>

#define HW 2304           // 48*48
#define O192 192
#define SCALE_F 0.35355339059327373f   // 8^-0.5

typedef unsigned int u32;
typedef __attribute__((address_space(1))) const u32 gu32;
typedef __attribute__((address_space(3))) u32 lu32;
// async global->LDS DMA, 16B per lane; LDS dest = wave-uniform base + lane*16
__device__ __forceinline__ void dma16(const void* g, void* l) {
  __builtin_amdgcn_global_load_lds((gu32*)g, (lu32*)l, 16, 0, 0);
}

// ---------------- Kernel A: 1x1 conv -> q,k (QKV) and v (V2) ----------------
__global__ __launch_bounds__(256) void qkv_kernel(
    const float* __restrict__ F, const float* __restrict__ W,
    float* __restrict__ QKV, float* __restrict__ V2) {
  __shared__ __align__(16) float sW[384];   // two o0 sets x {q,k,v} rows x 64
  int blk = blockIdx.x;
  int idx0 = blk * 256;
  int r0 = idx0 / HW;
  int r1 = (idx0 + 255) / HW;
  int tid = threadIdx.x;
  if (tid < 192) {
    int g = tid >> 6, c = tid & 63;
    sW[tid]       = W[((r0 & 63) + g * 64) * 64 + c];
    sW[192 + tid] = W[((r1 & 63) + g * 64) * 64 + c];
  }
  __syncthreads();
  int idx = idx0 + tid;
  int p  = idx % HW;
  int r  = idx / HW;
  int o0 = r & 63;
  int b  = r >> 6;
  const float4* w4 = (const float4*)(sW + ((r == r0) ? 0 : 192));
  const float* f = F + (b * 64) * HW + p;
  float aq = 0.f, ak = 0.f, av = 0.f;
  #pragma unroll 4
  for (int c4 = 0; c4 < 16; c4++) {
    float4 wq = w4[c4];
    float4 wk = w4[16 + c4];
    float4 wv = w4[32 + c4];
    float f0 = f[(c4 * 4 + 0) * HW];
    float f1 = f[(c4 * 4 + 1) * HW];
    float f2 = f[(c4 * 4 + 2) * HW];
    float f3 = f[(c4 * 4 + 3) * HW];
    aq = fmaf(wq.x, f0, aq); ak = fmaf(wk.x, f0, ak); av = fmaf(wv.x, f0, av);
    aq = fmaf(wq.y, f1, aq); ak = fmaf(wk.y, f1, ak); av = fmaf(wv.y, f1, av);
    aq = fmaf(wq.z, f2, aq); ak = fmaf(wk.z, f2, ak); av = fmaf(wv.z, f2, av);
    aq = fmaf(wq.w, f3, aq); ak = fmaf(wk.w, f3, ak); av = fmaf(wv.w, f3, av);
  }
  float* qp = QKV + (b * HW + p) * O192;
  qp[o0]      = aq;
  qp[o0 + 64] = ak;
  V2[(((b << 3) + (o0 >> 3)) * HW + p) * 8 + (o0 & 7)] = av;
}

// ---------------- Kernel B: 11x11 stride-8 conv + bias + exact GELU ----------
__global__ __launch_bounds__(256) void conv_kernel(
    const float* __restrict__ QKV, const float* __restrict__ Wq,
    const float* __restrict__ Bq, const float* __restrict__ Wk,
    const float* __restrict__ Bk, float* __restrict__ QD) {
  __shared__ float sW[7744];
  __shared__ float sRed[4 * 64 * 6];
  int blk = blockIdx.x;
  int xcd = blk & 7;
  int T = xcd >> 2, b = (xcd >> 1) & 1, s = xcd & 1;
  int idx = (blk >> 3) * 2 + s;
  int o  = idx / 6;
  int oy = idx % 6;
  const float* Wg = T ? Wk : Wq;
  for (int i = threadIdx.x; i < 7744; i += 256) sW[i] = Wg[o * 7744 + i];
  __syncthreads();
  int wv = threadIdx.x >> 6;
  int c  = threadIdx.x & 63;
  const float* base = QKV + b * (HW * O192) + T * 64 + c;
  float acc[6];
  #pragma unroll
  for (int ox = 0; ox < 6; ox++) acc[ox] = 0.f;
  for (int kyi = 0; kyi < 3; kyi++) {
    int ky = wv * 3 + kyi;
    if (ky > 10) break;
    int y = oy * 8 - 2 + ky;
    if ((unsigned)y < 48u) {
      float xrow[48];
      #pragma unroll
      for (int x = 0; x < 48; x++) xrow[x] = base[(y * 48 + x) * O192];
      #pragma unroll
      for (int kx = 0; kx < 11; kx++) {
        float wt = sW[c * 121 + ky * 11 + kx];
        #pragma unroll
        for (int ox = 0; ox < 6; ox++) {
          int x = ox * 8 - 2 + kx;
          if (x >= 0 && x < 48) acc[ox] = fmaf(xrow[x], wt, acc[ox]);
        }
      }
    }
  }
  #pragma unroll
  for (int ox = 0; ox < 6; ox++) sRed[(wv * 64 + c) * 6 + ox] = acc[ox];
  __syncthreads();
  if (threadIdx.x < 64) {
    int t = threadIdx.x;
    float r[6];
    #pragma unroll
    for (int ox = 0; ox < 6; ox++)
      r[ox] = sRed[t * 6 + ox] + sRed[(64 + t) * 6 + ox]
            + sRed[(128 + t) * 6 + ox] + sRed[(192 + t) * 6 + ox];
    #pragma unroll
    for (int off = 32; off; off >>= 1) {
      #pragma unroll
      for (int ox = 0; ox < 6; ox++) r[ox] += __shfl_down(r[ox], off, 64);
    }
    if (t == 0) {
      float bias = T ? Bk[o] : Bq[o];
      #pragma unroll
      for (int ox = 0; ox < 6; ox++) {
        float g = r[ox] + bias;
        float ge = 0.5f * g * (1.0f + erff(g * 0.70710678118654752f));
        QD[((T * 2 + b) * 64 + o) * 36 + oy * 6 + ox] = ge;
      }
    }
  }
}

// ---------------- Kernel C: full-j attention, v3 ----------------------------
// Lessons baked in: no device fences (r1); no forced min-occupancy (r2);
// V must be LDS-staged, NOT read from L2 in the loop (r4: broadcast global
// loads -> vmcnt-bound, 94us); fine grain for balance + transposed sQ (r3->r4
// wins). This round: r4 grain (1152 blocks x 32 rows, 4 blk/CU) + r3's dma16
// V-quarter staging + DMA latency covered by building the NEXT quarter's eA
// slice between DMA issue and the drain barrier (T14 issue-early pattern).
// Block = (bh:16, S:72 of 32 rows). 512 thr = 8 waves; rl = lane&31 = row,
// jx-group g = w*2+(lane>>5) in [0,16), 3 jx each. acc[9]/lane; pair-reduce
// shfl_xor(32), then one LDS round over 8 waves.
#define OFF_V   0        // 4608 f : V quarter [12jy][48jx][8c]
#define OFF_EA  4608     // 1536 f : eA [jy 0..47][rl 0..31]
#define OFF_PHT 6144     // 384  f : PH^T [jy][c]
#define OFF_PWT 6528     // 384  f : PW^T [jx][c]
#define OFF_E   6912     // 36+4 f : E [J]
#define OFF_QT  6952     // 256  f : sQT [c][row]  (transposed)
#define OFF_R   7208     // 2304 f : sRed [8 waves][32 rows][9]
#define SBUF_N  9512     // 38048 B -> 4 blocks/CU (wave-slot bound)

__global__ __launch_bounds__(512, 4) void attn_kernel(
    const float* __restrict__ QKV, const float* __restrict__ V2,
    const float* __restrict__ QD, const float* __restrict__ PH,
    const float* __restrict__ PW, float* __restrict__ out) {
  __shared__ __align__(16) float sB[SBUF_N];
  int blk = blockIdx.x;
  int bh = blk / 72;
  int S  = blk - bh * 72;         // 32-row supertile; I column = S>>1
  int b = bh >> 3, h = bh & 7;
  int tid = threadIdx.x;
  int w = tid >> 6, lane = tid & 63;
  int rl = lane & 31;             // row within tile
  int g  = w * 2 + (lane >> 5);   // jx-group in [0,16), 3 jx each
  // ---- stage tables + issue V-quarter-0 DMA ----
  if (tid < 384) {
    sB[OFF_PHT + tid] = PH[(tid & 7) * 48 + (tid >> 3)];
    sB[OFF_PWT + tid] = PW[(tid & 7) * 48 + (tid >> 3)];
  }
  if (tid < 36) {   // fused dots: E[J] = exp(SCALE * qd[:,I].kd[:,J])
    int I = S >> 1;
    float acc = 0.f;
    #pragma unroll
    for (int c8 = 0; c8 < 8; c8++) {
      float qv = QD[((0 + b) * 64 + h * 8 + c8) * 36 + I];
      float kv = QD[((2 + b) * 64 + h * 8 + c8) * 36 + tid];
      acc = fmaf(qv, kv, acc);
    }
    sB[OFF_E + tid] = __expf(SCALE_F * acc);
  }
  if (tid < 256) {  // sQT[c][row]: coalesced-ish global, conflict-free LDS
    int row = tid >> 3, c = tid & 7;
    sB[OFF_QT + c * 32 + row] =
      QKV[(b * HW + S * 32 + row) * O192 + h * 8 + c];
  }
  const char* vsrc = (const char*)(V2 + (size_t)bh * (HW * 8));
  for (int m = w; m < 18; m += 8)
    dma16(vsrc + m * 1024 + lane * 16, (char*)(sB + OFF_V) + m * 1024);
  __syncthreads();   // publish QT/tables; drains V(0) DMA
  // ---- eB regs: this lane's 3 jx for its row ----
  float eB[3];
  #pragma unroll
  for (int i = 0; i < 3; i++) {
    const float* pp = sB + OFF_PWT + (g * 3 + i) * 8;
    float d = 0.f;
    #pragma unroll
    for (int j = 0; j < 8; j++) d = fmaf(sB[OFF_QT + j * 32 + rl], pp[j], d);
    eB[i] = __expf(d);
  }
  // ---- eA slice for quarter 0 (jy 0..11): 384 entries ----
  if (tid < 384) {
    int jy = tid >> 5, r = tid & 31;
    const float* pp = sB + OFF_PHT + jy * 8;
    float d = 0.f;
    #pragma unroll
    for (int j = 0; j < 8; j++) d = fmaf(sB[OFF_QT + j * 32 + r], pp[j], d);
    sB[OFF_EA + tid] = __expf(d);
  }
  __syncthreads();   // publish eA(0)
  // ---- main: 4 quarters x 12 jy; V broadcast from LDS ----
  float acc[9];
  #pragma unroll
  for (int c = 0; c < 9; c++) acc[c] = 0.f;
  const float4* sV4 = (const float4*)(sB + OFF_V);
  for (int q = 0; q < 4; q++) {
    for (int jyL = 0; jyL < 12; jyL++) {
      int jy = q * 12 + jyL;
      float eAk = sB[OFF_EA + jy * 32 + rl];
      int cb = jy * 48 + g * 3;                 // global j of i=0
      int J0 = cb >> 6, J1 = (cb + 2) >> 6;
      int ib = 64 - (cb & 63);                  // i >= ib uses J1
      float a0 = eAk * sB[OFF_E + J0];
      float a1 = eAk * sB[OFF_E + J1];
      #pragma unroll
      for (int i = 0; i < 3; i++) {
        float4 vlo = sV4[(jyL * 48 + g * 3 + i) * 2];
        float4 vhi = sV4[(jyL * 48 + g * 3 + i) * 2 + 1];
        float wgt = (i < ib ? a0 : a1) * eB[i];
        acc[0] = fmaf(wgt, vlo.x, acc[0]);
        acc[1] = fmaf(wgt, vlo.y, acc[1]);
        acc[2] = fmaf(wgt, vlo.z, acc[2]);
        acc[3] = fmaf(wgt, vlo.w, acc[3]);
        acc[4] = fmaf(wgt, vhi.x, acc[4]);
        acc[5] = fmaf(wgt, vhi.y, acc[5]);
        acc[6] = fmaf(wgt, vhi.z, acc[6]);
        acc[7] = fmaf(wgt, vhi.w, acc[7]);
        acc[8] += wgt;
      }
    }
    if (q < 3) {
      __syncthreads();   // all waves done reading V(q)
      // issue V(q+1) DMA, then cover its latency with the eA(q+1) slice
      for (int m = w; m < 18; m += 8)
        dma16(vsrc + (q + 1) * 18432 + m * 1024 + lane * 16,
              (char*)(sB + OFF_V) + m * 1024);
      if (tid < 384) {
        int flat = (q + 1) * 384 + tid;
        int jy = flat >> 5, r = flat & 31;
        const float* pp = sB + OFF_PHT + jy * 8;
        float d = 0.f;
        #pragma unroll
        for (int j = 0; j < 8; j++) d = fmaf(sB[OFF_QT + j * 32 + r], pp[j], d);
        sB[OFF_EA + flat] = __expf(d);
      }
      __syncthreads();   // drain V(q+1) DMA; publish eA(q+1)
    }
  }
  // ---- reduce: pair (lane-halves) via shfl, then across 8 waves via LDS ----
  #pragma unroll
  for (int c = 0; c < 9; c++) acc[c] += __shfl_xor(acc[c], 32, 64);
  if (lane < 32) {
    #pragma unroll
    for (int c = 0; c < 9; c++) sB[OFF_R + (w * 32 + rl) * 9 + c] = acc[c];
  }
  __syncthreads();
  if (tid < 256) {
    int r = tid & 31, c = tid >> 5;   // c in 0..7
    float num = 0.f, z = 0.f;
    #pragma unroll
    for (int ww = 0; ww < 8; ww++) {
      num += sB[OFF_R + (ww * 32 + r) * 9 + c];
      z   += sB[OFF_R + (ww * 32 + r) * 9 + 8];
    }
    out[(b * 64 + h * 8 + c) * HW + S * 32 + r] = num / z;
  }
}

extern "C" void kernel_launch(void* const* d_in, const int* in_sizes, int n_in,
                              void* d_out, int out_size, void* d_ws, size_t ws_size,
                              hipStream_t stream) {
  const float* F    = (const float*)d_in[0];
  const float* Wqkv = (const float*)d_in[1];
  const float* Wq   = (const float*)d_in[2];
  const float* Bq   = (const float*)d_in[3];
  const float* Wk   = (const float*)d_in[4];
  const float* Bk   = (const float*)d_in[5];
  const float* PH   = (const float*)d_in[6];
  const float* PW   = (const float*)d_in[7];
  float* out = (float*)d_out;

  float* ws   = (float*)d_ws;
  float* QKV  = ws;                        // 884736 f
  float* V2   = QKV + 2 * HW * O192;       // 294912 f
  float* QD   = V2 + 2 * 8 * HW * 8;       // 9216 f   (~4.8 MB total)

  qkv_kernel <<<1152, 256, 0, stream>>>(F, Wqkv, QKV, V2);
  conv_kernel<<<1536, 256, 0, stream>>>(QKV, Wq, Bq, Wk, Bk, QD);
  attn_kernel<<<1152, 512, 0, stream>>>(QKV, V2, QD, PH, PW, out);
}

// Round 6
// 260.615 us; speedup vs baseline: 3.8603x; 3.8603x over previous
//
#include <hip/hip_runtime.h>
#include <math.h>

#define HW 2304           // 48*48
#define O192 192
#define SCALE_F 0.35355339059327373f   // 8^-0.5

typedef unsigned int u32;
typedef __attribute__((address_space(1))) const u32 gu32;
typedef __attribute__((address_space(3))) u32 lu32;
// async global->LDS DMA, 16B per lane; LDS dest = wave-uniform base + lane*16
__device__ __forceinline__ void dma16(const void* g, void* l) {
  __builtin_amdgcn_global_load_lds((gu32*)g, (lu32*)l, 16, 0, 0);
}

// ---------------- Kernel A: 1x1 conv -> q,k (QKV) and v (V2) ----------------
__global__ __launch_bounds__(256) void qkv_kernel(
    const float* __restrict__ F, const float* __restrict__ W,
    float* __restrict__ QKV, float* __restrict__ V2) {
  __shared__ __align__(16) float sW[384];   // two o0 sets x {q,k,v} rows x 64
  int blk = blockIdx.x;
  int idx0 = blk * 256;
  int r0 = idx0 / HW;
  int r1 = (idx0 + 255) / HW;
  int tid = threadIdx.x;
  if (tid < 192) {
    int g = tid >> 6, c = tid & 63;
    sW[tid]       = W[((r0 & 63) + g * 64) * 64 + c];
    sW[192 + tid] = W[((r1 & 63) + g * 64) * 64 + c];
  }
  __syncthreads();
  int idx = idx0 + tid;
  int p  = idx % HW;
  int r  = idx / HW;
  int o0 = r & 63;
  int b  = r >> 6;
  const float4* w4 = (const float4*)(sW + ((r == r0) ? 0 : 192));
  const float* f = F + (b * 64) * HW + p;
  float aq = 0.f, ak = 0.f, av = 0.f;
  #pragma unroll 4
  for (int c4 = 0; c4 < 16; c4++) {
    float4 wq = w4[c4];
    float4 wk = w4[16 + c4];
    float4 wv = w4[32 + c4];
    float f0 = f[(c4 * 4 + 0) * HW];
    float f1 = f[(c4 * 4 + 1) * HW];
    float f2 = f[(c4 * 4 + 2) * HW];
    float f3 = f[(c4 * 4 + 3) * HW];
    aq = fmaf(wq.x, f0, aq); ak = fmaf(wk.x, f0, ak); av = fmaf(wv.x, f0, av);
    aq = fmaf(wq.y, f1, aq); ak = fmaf(wk.y, f1, ak); av = fmaf(wv.y, f1, av);
    aq = fmaf(wq.z, f2, aq); ak = fmaf(wk.z, f2, ak); av = fmaf(wv.z, f2, av);
    aq = fmaf(wq.w, f3, aq); ak = fmaf(wk.w, f3, ak); av = fmaf(wv.w, f3, av);
  }
  float* qp = QKV + (b * HW + p) * O192;
  qp[o0]      = aq;
  qp[o0 + 64] = ak;
  V2[(((b << 3) + (o0 >> 3)) * HW + p) * 8 + (o0 & 7)] = av;
}

// ---------------- Kernel B: 11x11 stride-8 conv + bias + exact GELU ----------
__global__ __launch_bounds__(256) void conv_kernel(
    const float* __restrict__ QKV, const float* __restrict__ Wq,
    const float* __restrict__ Bq, const float* __restrict__ Wk,
    const float* __restrict__ Bk, float* __restrict__ QD) {
  __shared__ float sW[7744];
  __shared__ float sRed[4 * 64 * 6];
  int blk = blockIdx.x;
  int xcd = blk & 7;
  int T = xcd >> 2, b = (xcd >> 1) & 1, s = xcd & 1;
  int idx = (blk >> 3) * 2 + s;
  int o  = idx / 6;
  int oy = idx % 6;
  const float* Wg = T ? Wk : Wq;
  for (int i = threadIdx.x; i < 7744; i += 256) sW[i] = Wg[o * 7744 + i];
  __syncthreads();
  int wv = threadIdx.x >> 6;
  int c  = threadIdx.x & 63;
  const float* base = QKV + b * (HW * O192) + T * 64 + c;
  float acc[6];
  #pragma unroll
  for (int ox = 0; ox < 6; ox++) acc[ox] = 0.f;
  for (int kyi = 0; kyi < 3; kyi++) {
    int ky = wv * 3 + kyi;
    if (ky > 10) break;
    int y = oy * 8 - 2 + ky;
    if ((unsigned)y < 48u) {
      float xrow[48];
      #pragma unroll
      for (int x = 0; x < 48; x++) xrow[x] = base[(y * 48 + x) * O192];
      #pragma unroll
      for (int kx = 0; kx < 11; kx++) {
        float wt = sW[c * 121 + ky * 11 + kx];
        #pragma unroll
        for (int ox = 0; ox < 6; ox++) {
          int x = ox * 8 - 2 + kx;
          if (x >= 0 && x < 48) acc[ox] = fmaf(xrow[x], wt, acc[ox]);
        }
      }
    }
  }
  #pragma unroll
  for (int ox = 0; ox < 6; ox++) sRed[(wv * 64 + c) * 6 + ox] = acc[ox];
  __syncthreads();
  if (threadIdx.x < 64) {
    int t = threadIdx.x;
    float r[6];
    #pragma unroll
    for (int ox = 0; ox < 6; ox++)
      r[ox] = sRed[t * 6 + ox] + sRed[(64 + t) * 6 + ox]
            + sRed[(128 + t) * 6 + ox] + sRed[(192 + t) * 6 + ox];
    #pragma unroll
    for (int off = 32; off; off >>= 1) {
      #pragma unroll
      for (int ox = 0; ox < 6; ox++) r[ox] += __shfl_down(r[ox], off, 64);
    }
    if (t == 0) {
      float bias = T ? Bk[o] : Bq[o];
      #pragma unroll
      for (int ox = 0; ox < 6; ox++) {
        float g = r[ox] + bias;
        float ge = 0.5f * g * (1.0f + erff(g * 0.70710678118654752f));
        QD[((T * 2 + b) * 64 + o) * 36 + oy * 6 + ox] = ge;
      }
    }
  }
}

// ---------------- Kernel C: full-j attention (r3 shell, 2 rows/lane) --------
// Shell identical to the verified 45.6us round-3 kernel: 576 blocks =
// (bh:16, S:36 of 64 rows), 512 thr, same DMA quarters + barrier cadence,
// same epilogue. SINGLE delta: each lane owns TWO rows (rl, rl+32) and 3 jx
// (16 jx-groups, g=2w+(lane>>5), structure r4 already ran cleanly) -> the
// same 54 fma/lane/jy now needs 6 ds_read_b128 instead of 12 (V broadcast
// amortized over 2 rows). Plus r4's verified transposed sQT (conflicts
// 258K->64K). Lessons kept: no device fences (r1), no forced min-occupancy
// (r2), V LDS-staged not L2-read (r4).
#define OFF_V   0        // 4608 f : V quarter [12jy][48jx][8c]
#define OFF_EA  4608     // 768  f : eA [jyL][row 0..63]
#define OFF_PHT 5376     // 384  f : PH^T [jy][c]
#define OFF_PWT 5760     // 384  f : PW^T [jx][c]
#define OFF_E   6144     // 36+4 f : E [J]
#define OFF_QT  6184     // 512  f : sQT [c][row]  (transposed)
#define OFF_R   6696     // 4608 f : sRed [8 waves][64 rows][9]
#define SBUF_N  11304    // 45216 B -> 3 blocks/CU (same as r3)

__global__ __launch_bounds__(512, 4) void attn_kernel(
    const float* __restrict__ QKV, const float* __restrict__ V2,
    const float* __restrict__ QD, const float* __restrict__ PH,
    const float* __restrict__ PW, float* __restrict__ out) {
  __shared__ __align__(16) float sB[SBUF_N];
  int blk = blockIdx.x;
  int bh = blk / 36;
  int S  = blk - bh * 36;         // 64-row supertile == I column
  int b = bh >> 3, h = bh & 7;
  int tid = threadIdx.x;
  int w = tid >> 6, lane = tid & 63;
  int rl = lane & 31;             // first owned row; second is rl+32
  int g  = w * 2 + (lane >> 5);   // jx-group in [0,16), 3 jx each
  // ---- stage tables ----
  if (tid < 384) {
    sB[OFF_PHT + tid] = PH[(tid & 7) * 48 + (tid >> 3)];
    sB[OFF_PWT + tid] = PW[(tid & 7) * 48 + (tid >> 3)];
  }
  if (tid < 36) {   // fused dots: E[J] = exp(SCALE * qd[:,S].kd[:,J])
    float acc = 0.f;
    #pragma unroll
    for (int c8 = 0; c8 < 8; c8++) {
      float qv = QD[((0 + b) * 64 + h * 8 + c8) * 36 + S];
      float kv = QD[((2 + b) * 64 + h * 8 + c8) * 36 + tid];
      acc = fmaf(qv, kv, acc);
    }
    sB[OFF_E + tid] = __expf(SCALE_F * acc);
  }
  {  // sQT[c][row]: global-coalesced (8 consecutive floats per row-octet)
    int row = tid >> 3, c = tid & 7;
    sB[OFF_QT + c * 64 + row] =
      QKV[(b * HW + S * 64 + row) * O192 + h * 8 + c];
  }
  { // V quarter 0 via DMA: 18 chunks x 1 KiB
    const char* src = (const char*)(V2 + (size_t)bh * (HW * 8));
    for (int m = w; m < 18; m += 8)
      dma16(src + m * 1024 + lane * 16, (char*)(sB + OFF_V) + m * 1024);
  }
  __syncthreads();   // publish tables/QT; drains V(0) DMA
  // ---- eB regs: 2 rows x 3 jx ----
  float eB[2][3];
  #pragma unroll
  for (int k = 0; k < 2; k++) {
    int row = rl + k * 32;
    #pragma unroll
    for (int i = 0; i < 3; i++) {
      const float* pp = sB + OFF_PWT + (g * 3 + i) * 8;
      float d = 0.f;
      #pragma unroll
      for (int j = 0; j < 8; j++) d = fmaf(sB[OFF_QT + j * 64 + row], pp[j], d);
      eB[k][i] = __expf(d);
    }
  }
  // ---- main: 4 quarters x 12 jy; V broadcast from LDS ----
  float acc0[9], acc1[9];
  #pragma unroll
  for (int c = 0; c < 9; c++) { acc0[c] = 0.f; acc1[c] = 0.f; }
  const float4* sV4 = (const float4*)(sB + OFF_V);
  for (int q = 0; q < 4; q++) {
    // eA(q): exp(q_row . PH[:, q*12+jyL]), 768 entries [jyL][row]
    #pragma unroll
    for (int m = 0; m < 2; m++) {
      int flat = tid + m * 512;
      if (flat < 768) {
        int jyL = flat >> 6, row = flat & 63;
        const float* pp = sB + OFF_PHT + (q * 12 + jyL) * 8;
        float d = 0.f;
        #pragma unroll
        for (int j = 0; j < 8; j++) d = fmaf(sB[OFF_QT + j * 64 + row], pp[j], d);
        sB[OFF_EA + flat] = __expf(d);
      }
    }
    __syncthreads();   // publish eA(q); (for q>0 also pairs with prefetch drain)
    for (int jyL = 0; jyL < 12; jyL++) {
      float eA0 = sB[OFF_EA + jyL * 64 + rl];
      float eA1 = sB[OFF_EA + jyL * 64 + rl + 32];
      int cb = (q * 12 + jyL) * 48 + g * 3;     // global j of i=0
      int J0 = cb >> 6, J1 = (cb + 2) >> 6;
      int ib = 64 - (cb & 63);                  // i >= ib uses J1
      float e0 = sB[OFF_E + J0];
      float e1 = sB[OFF_E + J1];
      float a00 = eA0 * e0, a01 = eA0 * e1;
      float a10 = eA1 * e0, a11 = eA1 * e1;
      #pragma unroll
      for (int i = 0; i < 3; i++) {
        float4 vlo = sV4[(jyL * 48 + g * 3 + i) * 2];
        float4 vhi = sV4[(jyL * 48 + g * 3 + i) * 2 + 1];
        bool sel = (i < ib);
        float w0 = (sel ? a00 : a01) * eB[0][i];
        float w1 = (sel ? a10 : a11) * eB[1][i];
        acc0[0] = fmaf(w0, vlo.x, acc0[0]);  acc1[0] = fmaf(w1, vlo.x, acc1[0]);
        acc0[1] = fmaf(w0, vlo.y, acc0[1]);  acc1[1] = fmaf(w1, vlo.y, acc1[1]);
        acc0[2] = fmaf(w0, vlo.z, acc0[2]);  acc1[2] = fmaf(w1, vlo.z, acc1[2]);
        acc0[3] = fmaf(w0, vlo.w, acc0[3]);  acc1[3] = fmaf(w1, vlo.w, acc1[3]);
        acc0[4] = fmaf(w0, vhi.x, acc0[4]);  acc1[4] = fmaf(w1, vhi.x, acc1[4]);
        acc0[5] = fmaf(w0, vhi.y, acc0[5]);  acc1[5] = fmaf(w1, vhi.y, acc1[5]);
        acc0[6] = fmaf(w0, vhi.z, acc0[6]);  acc1[6] = fmaf(w1, vhi.z, acc1[6]);
        acc0[7] = fmaf(w0, vhi.w, acc0[7]);  acc1[7] = fmaf(w1, vhi.w, acc1[7]);
        acc0[8] += w0;                        acc1[8] += w1;
      }
    }
    if (q < 3) {
      __syncthreads();   // all waves done reading V(q)/eA(q)
      const char* src = (const char*)(V2 + (size_t)bh * (HW * 8) + (size_t)(q + 1) * 4608);
      for (int m = w; m < 18; m += 8)
        dma16(src + m * 1024 + lane * 16, (char*)(sB + OFF_V) + m * 1024);
      // latency covered by next iteration's eA build; its barrier drains DMA
    }
  }
  // ---- reduce: combine the wave's 2 jx-groups via shfl, then 8 waves ------
  #pragma unroll
  for (int c = 0; c < 9; c++) {
    acc0[c] += __shfl_xor(acc0[c], 32, 64);
    acc1[c] += __shfl_xor(acc1[c], 32, 64);
  }
  if (lane < 32) {
    #pragma unroll
    for (int c = 0; c < 9; c++) {
      sB[OFF_R + (w * 64 + rl) * 9 + c]      = acc0[c];
      sB[OFF_R + (w * 64 + rl + 32) * 9 + c] = acc1[c];
    }
  }
  __syncthreads();
  {
    int c = tid >> 6, r = tid & 63;
    float num = 0.f, z = 0.f;
    #pragma unroll
    for (int ww = 0; ww < 8; ww++) {
      num += sB[OFF_R + (ww * 64 + r) * 9 + c];
      z   += sB[OFF_R + (ww * 64 + r) * 9 + 8];
    }
    out[(b * 64 + h * 8 + c) * HW + S * 64 + r] = num / z;
  }
}

extern "C" void kernel_launch(void* const* d_in, const int* in_sizes, int n_in,
                              void* d_out, int out_size, void* d_ws, size_t ws_size,
                              hipStream_t stream) {
  const float* F    = (const float*)d_in[0];
  const float* Wqkv = (const float*)d_in[1];
  const float* Wq   = (const float*)d_in[2];
  const float* Bq   = (const float*)d_in[3];
  const float* Wk   = (const float*)d_in[4];
  const float* Bk   = (const float*)d_in[5];
  const float* PH   = (const float*)d_in[6];
  const float* PW   = (const float*)d_in[7];
  float* out = (float*)d_out;

  float* ws   = (float*)d_ws;
  float* QKV  = ws;                        // 884736 f
  float* V2   = QKV + 2 * HW * O192;       // 294912 f
  float* QD   = V2 + 2 * 8 * HW * 8;       // 9216 f   (~4.8 MB total)

  qkv_kernel <<<1152, 256, 0, stream>>>(F, Wqkv, QKV, V2);
  conv_kernel<<<1536, 256, 0, stream>>>(QKV, Wq, Bq, Wk, Bk, QD);
  attn_kernel<<<576,  512, 0, stream>>>(QKV, V2, QD, PH, PW, out);
}

// Round 7
// 136.271 us; speedup vs baseline: 7.3828x; 1.9125x over previous
//
#include <hip/hip_runtime.h>
#include <math.h>

#define HW 2304           // 48*48
#define O192 192
#define SCALE_F 0.35355339059327373f   // 8^-0.5

typedef unsigned int u32;
typedef __attribute__((address_space(1))) const u32 gu32;
typedef __attribute__((address_space(3))) u32 lu32;
// async global->LDS DMA, 16B per lane; LDS dest = wave-uniform base + lane*16
__device__ __forceinline__ void dma16(const void* g, void* l) {
  __builtin_amdgcn_global_load_lds((gu32*)g, (lu32*)l, 16, 0, 0);
}

// ---------------- Kernel A: 1x1 conv -> q,k (QKV) and v (V2) ----------------
__global__ __launch_bounds__(256) void qkv_kernel(
    const float* __restrict__ F, const float* __restrict__ W,
    float* __restrict__ QKV, float* __restrict__ V2) {
  __shared__ __align__(16) float sW[384];   // two o0 sets x {q,k,v} rows x 64
  int blk = blockIdx.x;
  int idx0 = blk * 256;
  int r0 = idx0 / HW;
  int r1 = (idx0 + 255) / HW;
  int tid = threadIdx.x;
  if (tid < 192) {
    int g = tid >> 6, c = tid & 63;
    sW[tid]       = W[((r0 & 63) + g * 64) * 64 + c];
    sW[192 + tid] = W[((r1 & 63) + g * 64) * 64 + c];
  }
  __syncthreads();
  int idx = idx0 + tid;
  int p  = idx % HW;
  int r  = idx / HW;
  int o0 = r & 63;
  int b  = r >> 6;
  const float4* w4 = (const float4*)(sW + ((r == r0) ? 0 : 192));
  const float* f = F + (b * 64) * HW + p;
  float aq = 0.f, ak = 0.f, av = 0.f;
  #pragma unroll 4
  for (int c4 = 0; c4 < 16; c4++) {
    float4 wq = w4[c4];
    float4 wk = w4[16 + c4];
    float4 wv = w4[32 + c4];
    float f0 = f[(c4 * 4 + 0) * HW];
    float f1 = f[(c4 * 4 + 1) * HW];
    float f2 = f[(c4 * 4 + 2) * HW];
    float f3 = f[(c4 * 4 + 3) * HW];
    aq = fmaf(wq.x, f0, aq); ak = fmaf(wk.x, f0, ak); av = fmaf(wv.x, f0, av);
    aq = fmaf(wq.y, f1, aq); ak = fmaf(wk.y, f1, ak); av = fmaf(wv.y, f1, av);
    aq = fmaf(wq.z, f2, aq); ak = fmaf(wk.z, f2, ak); av = fmaf(wv.z, f2, av);
    aq = fmaf(wq.w, f3, aq); ak = fmaf(wk.w, f3, ak); av = fmaf(wv.w, f3, av);
  }
  float* qp = QKV + (b * HW + p) * O192;
  qp[o0]      = aq;
  qp[o0 + 64] = ak;
  V2[(((b << 3) + (o0 >> 3)) * HW + p) * 8 + (o0 & 7)] = av;
}

// ---------------- Kernel B: 11x11 stride-8 conv + bias + exact GELU ----------
__global__ __launch_bounds__(256) void conv_kernel(
    const float* __restrict__ QKV, const float* __restrict__ Wq,
    const float* __restrict__ Bq, const float* __restrict__ Wk,
    const float* __restrict__ Bk, float* __restrict__ QD) {
  __shared__ float sW[7744];
  __shared__ float sRed[4 * 64 * 6];
  int blk = blockIdx.x;
  int xcd = blk & 7;
  int T = xcd >> 2, b = (xcd >> 1) & 1, s = xcd & 1;
  int idx = (blk >> 3) * 2 + s;
  int o  = idx / 6;
  int oy = idx % 6;
  const float* Wg = T ? Wk : Wq;
  for (int i = threadIdx.x; i < 7744; i += 256) sW[i] = Wg[o * 7744 + i];
  __syncthreads();
  int wv = threadIdx.x >> 6;
  int c  = threadIdx.x & 63;
  const float* base = QKV + b * (HW * O192) + T * 64 + c;
  float acc[6];
  #pragma unroll
  for (int ox = 0; ox < 6; ox++) acc[ox] = 0.f;
  for (int kyi = 0; kyi < 3; kyi++) {
    int ky = wv * 3 + kyi;
    if (ky > 10) break;
    int y = oy * 8 - 2 + ky;
    if ((unsigned)y < 48u) {
      float xrow[48];
      #pragma unroll
      for (int x = 0; x < 48; x++) xrow[x] = base[(y * 48 + x) * O192];
      #pragma unroll
      for (int kx = 0; kx < 11; kx++) {
        float wt = sW[c * 121 + ky * 11 + kx];
        #pragma unroll
        for (int ox = 0; ox < 6; ox++) {
          int x = ox * 8 - 2 + kx;
          if (x >= 0 && x < 48) acc[ox] = fmaf(xrow[x], wt, acc[ox]);
        }
      }
    }
  }
  #pragma unroll
  for (int ox = 0; ox < 6; ox++) sRed[(wv * 64 + c) * 6 + ox] = acc[ox];
  __syncthreads();
  if (threadIdx.x < 64) {
    int t = threadIdx.x;
    float r[6];
    #pragma unroll
    for (int ox = 0; ox < 6; ox++)
      r[ox] = sRed[t * 6 + ox] + sRed[(64 + t) * 6 + ox]
            + sRed[(128 + t) * 6 + ox] + sRed[(192 + t) * 6 + ox];
    #pragma unroll
    for (int off = 32; off; off >>= 1) {
      #pragma unroll
      for (int ox = 0; ox < 6; ox++) r[ox] += __shfl_down(r[ox], off, 64);
    }
    if (t == 0) {
      float bias = T ? Bk[o] : Bq[o];
      #pragma unroll
      for (int ox = 0; ox < 6; ox++) {
        float g = r[ox] + bias;
        float ge = 0.5f * g * (1.0f + erff(g * 0.70710678118654752f));
        QD[((T * 2 + b) * 64 + o) * 36 + oy * 6 + ox] = ge;
      }
    }
  }
}

// ---------------- Kernel C: full-j attention (r3 structure, fine grain) -----
// Lessons: no device fences (r1); V LDS-staged via dma16, never L2-read in
// loop (r4); NEVER let launch_bounds cap VGPR at/below natural demand --
// r2/r5/r6's "mystery" GB-scale FETCH/WRITE was scratch spill from the cap
// (empirically cap ~= 256/min_waves_arg; all spill runs sat AT the cap).
// This round: r3's per-lane structure UNCHANGED (1 row/lane, 6 jx/lane,
// dma16 V quarters, same barrier cadence), re-grained to 1152 blocks x
// 256 thr x 32 rows. LDS 28.8KB, VGPR ~48 -> 5 blocks/CU -> all 1152
// resident in one batch (r3's 576 heavy blocks at 2/CU had a 45% tail).
#define OFF_V   0        // 4608 f : V quarter [12jy][48jx][8c]
#define OFF_EA  4608     // 384  f : eA [jyL][row 0..31]
#define OFF_PHT 4992     // 384  f : PH^T [jy][c]
#define OFF_PWT 5376     // 384  f : PW^T [jx][c]
#define OFF_E   5760     // 36+4 f : E [J]
#define OFF_QT  5800     // 256  f : sQT [c][row]  (transposed)
#define OFF_R   6056     // 1152 f : sRed [4 waves][32 rows][9]
#define SBUF_N  7208     // 28832 B -> 5 blocks/CU at VGPR<=51

__global__ __launch_bounds__(256) void attn_kernel(
    const float* __restrict__ QKV, const float* __restrict__ V2,
    const float* __restrict__ QD, const float* __restrict__ PH,
    const float* __restrict__ PW, float* __restrict__ out) {
  __shared__ __align__(16) float sB[SBUF_N];
  int blk = blockIdx.x;
  int bh = blk / 72;
  int S  = blk - bh * 72;         // 32-row supertile; I column = S>>1
  int b = bh >> 3, h = bh & 7;
  int tid = threadIdx.x;
  int w = tid >> 6, lane = tid & 63;   // 4 waves
  int rl = lane & 31;                  // owned row
  int g  = w * 2 + (lane >> 5);        // jx-group in [0,8), 6 jx each
  // ---- stage tables (256 threads -> strided over 384) ----
  for (int t = tid; t < 384; t += 256) {
    sB[OFF_PHT + t] = PH[(t & 7) * 48 + (t >> 3)];
    sB[OFF_PWT + t] = PW[(t & 7) * 48 + (t >> 3)];
  }
  if (tid < 36) {   // fused dots: E[J] = exp(SCALE * qd[:,I].kd[:,J])
    int I = S >> 1;
    float acc = 0.f;
    #pragma unroll
    for (int c8 = 0; c8 < 8; c8++) {
      float qv = QD[((0 + b) * 64 + h * 8 + c8) * 36 + I];
      float kv = QD[((2 + b) * 64 + h * 8 + c8) * 36 + tid];
      acc = fmaf(qv, kv, acc);
    }
    sB[OFF_E + tid] = __expf(SCALE_F * acc);
  }
  {  // sQT[c][row] transposed: 256 threads = 32 rows x 8 c
    int row = tid >> 3, c = tid & 7;
    sB[OFF_QT + c * 32 + row] =
      QKV[(b * HW + S * 32 + row) * O192 + h * 8 + c];
  }
  { // V quarter 0 via DMA: 18 chunks x 1 KiB over 4 waves
    const char* src = (const char*)(V2 + (size_t)bh * (HW * 8));
    for (int m = w; m < 18; m += 4)
      dma16(src + m * 1024 + lane * 16, (char*)(sB + OFF_V) + m * 1024);
  }
  __syncthreads();   // publish tables/QT; drains V(0) DMA
  // ---- eB regs: this lane's 6 jx for its row ----
  float eB[6];
  #pragma unroll
  for (int i = 0; i < 6; i++) {
    const float* pp = sB + OFF_PWT + (g * 6 + i) * 8;
    float d = 0.f;
    #pragma unroll
    for (int j = 0; j < 8; j++) d = fmaf(sB[OFF_QT + j * 32 + rl], pp[j], d);
    eB[i] = __expf(d);
  }
  // ---- main: 4 quarters x 12 jy; V broadcast from LDS ----
  float acc[9];
  #pragma unroll
  for (int c = 0; c < 9; c++) acc[c] = 0.f;
  const float4* sV4 = (const float4*)(sB + OFF_V);
  for (int q = 0; q < 4; q++) {
    // eA(q): exp(q_row . PH[:, q*12+jyL]), 384 entries [jyL][row]
    for (int t = tid; t < 384; t += 256) {
      int jyL = t >> 5, row = t & 31;
      const float* pp = sB + OFF_PHT + (q * 12 + jyL) * 8;
      float d = 0.f;
      #pragma unroll
      for (int j = 0; j < 8; j++) d = fmaf(sB[OFF_QT + j * 32 + row], pp[j], d);
      sB[OFF_EA + t] = __expf(d);
    }
    __syncthreads();   // publish eA(q); drains V(q) DMA (for q>0)
    for (int jyL = 0; jyL < 12; jyL++) {
      float eAk = sB[OFF_EA + jyL * 32 + rl];
      int cb = (q * 12 + jyL) * 48 + g * 6;     // global j of i=0
      int J0 = cb >> 6, J1 = (cb + 5) >> 6;
      int ib = 64 - (cb & 63);                  // i >= ib uses J1
      float a0 = eAk * sB[OFF_E + J0];
      float a1 = eAk * sB[OFF_E + J1];
      #pragma unroll
      for (int i = 0; i < 6; i++) {
        float4 vlo = sV4[(jyL * 48 + g * 6 + i) * 2];
        float4 vhi = sV4[(jyL * 48 + g * 6 + i) * 2 + 1];
        float wgt = (i < ib ? a0 : a1) * eB[i];
        acc[0] = fmaf(wgt, vlo.x, acc[0]);
        acc[1] = fmaf(wgt, vlo.y, acc[1]);
        acc[2] = fmaf(wgt, vlo.z, acc[2]);
        acc[3] = fmaf(wgt, vlo.w, acc[3]);
        acc[4] = fmaf(wgt, vhi.x, acc[4]);
        acc[5] = fmaf(wgt, vhi.y, acc[5]);
        acc[6] = fmaf(wgt, vhi.z, acc[6]);
        acc[7] = fmaf(wgt, vhi.w, acc[7]);
        acc[8] += wgt;
      }
    }
    if (q < 3) {
      __syncthreads();   // all waves done reading V(q)/eA(q)
      const char* src = (const char*)(V2 + (size_t)bh * (HW * 8) + (size_t)(q + 1) * 4608);
      for (int m = w; m < 18; m += 4)
        dma16(src + m * 1024 + lane * 16, (char*)(sB + OFF_V) + m * 1024);
      // latency covered by next quarter's eA build; its barrier drains DMA
    }
  }
  // ---- reduce: combine wave's 2 jx-groups via shfl, then 4 waves via LDS ---
  #pragma unroll
  for (int c = 0; c < 9; c++) acc[c] += __shfl_xor(acc[c], 32, 64);
  if (lane < 32) {
    #pragma unroll
    for (int c = 0; c < 9; c++) sB[OFF_R + (w * 32 + rl) * 9 + c] = acc[c];
  }
  __syncthreads();
  {
    int c = tid >> 5, r = tid & 31;   // 256 threads = 32 rows x 8 c
    float num = 0.f, z = 0.f;
    #pragma unroll
    for (int ww = 0; ww < 4; ww++) {
      num += sB[OFF_R + (ww * 32 + r) * 9 + c];
      z   += sB[OFF_R + (ww * 32 + r) * 9 + 8];
    }
    out[(b * 64 + h * 8 + c) * HW + S * 32 + r] = num / z;
  }
}

extern "C" void kernel_launch(void* const* d_in, const int* in_sizes, int n_in,
                              void* d_out, int out_size, void* d_ws, size_t ws_size,
                              hipStream_t stream) {
  const float* F    = (const float*)d_in[0];
  const float* Wqkv = (const float*)d_in[1];
  const float* Wq   = (const float*)d_in[2];
  const float* Bq   = (const float*)d_in[3];
  const float* Wk   = (const float*)d_in[4];
  const float* Bk   = (const float*)d_in[5];
  const float* PH   = (const float*)d_in[6];
  const float* PW   = (const float*)d_in[7];
  float* out = (float*)d_out;

  float* ws   = (float*)d_ws;
  float* QKV  = ws;                        // 884736 f
  float* V2   = QKV + 2 * HW * O192;       // 294912 f
  float* QD   = V2 + 2 * 8 * HW * 8;       // 9216 f   (~4.8 MB total)

  qkv_kernel <<<1152, 256, 0, stream>>>(F, Wqkv, QKV, V2);
  conv_kernel<<<1536, 256, 0, stream>>>(QKV, Wq, Bq, Wk, Bk, QD);
  attn_kernel<<<1152, 256, 0, stream>>>(QKV, V2, QD, PH, PW, out);
}